// Round 1
// baseline (321.476 us; speedup 1.0000x reference)
//
#include <hip/hip_runtime.h>
#include <math.h>

// B=4, N=256, D=256, H=8, DK=32, DV=32, R=64
constexpr int B_ = 4, N_ = 256, D_ = 256, H_ = 8, DK_ = 32, DV_ = 32, R_ = 64;
constexpr float SCALE_ = 0.17677669529663687f;  // 1/sqrt(32)
constexpr float EPS_ = 1e-6f;

// Ek = relationE @ Wr, Ev = relationE @ Wvv   ([64,256] @ [256,256] each)
// grid = 128 (64 rows x 2 outputs), block = 256
__global__ void ek_ev_kernel(const float* __restrict__ relE,
                             const float* __restrict__ Wr,
                             const float* __restrict__ Wvv,
                             float* __restrict__ Ek, float* __restrict__ Ev) {
    int r = blockIdx.x & 63;
    int which = blockIdx.x >> 6;
    const float* W = which ? Wvv : Wr;
    float* out = which ? Ev : Ek;
    __shared__ float row[256];
    int tid = threadIdx.x;
    row[tid] = relE[r * 256 + tid];
    __syncthreads();
    float acc = 0.f;
    for (int d = 0; d < 256; ++d) acc += row[d] * W[d * 256 + tid];
    out[r * 256 + tid] = acc;
}

// Xq/Xk/Xv projections with [b,h,n,dk] layout. grid = B*N = 1024, block = 256
__global__ void proj_kernel(const float* __restrict__ q,
                            const float* __restrict__ Wq,
                            const float* __restrict__ Wk,
                            const float* __restrict__ Wv,
                            float* __restrict__ Xq, float* __restrict__ Xk,
                            float* __restrict__ Xv) {
    int bn = blockIdx.x;           // b*N + n
    int b = bn >> 8, n = bn & 255;
    int tid = threadIdx.x;
    __shared__ float row[256];
    row[tid] = q[bn * 256 + tid];
    __syncthreads();
    float aq = 0.f, ak = 0.f, av = 0.f;
    for (int d = 0; d < 256; ++d) {
        float x = row[d];
        aq += x * Wq[d * 256 + tid];
        ak += x * Wk[d * 256 + tid];
        av += x * Wv[d * 256 + tid];
    }
    int h = tid >> 5, dk = tid & 31;
    int idx = ((b * H_ + h) * N_ + n) * 32 + dk;
    Xq[idx] = aq;
    Xk[idx] = ak;
    Xv[idx] = av;
}

// T[b,h,i,r] = sum_dk Xq[b,h,i,dk] * Ek[r, h*DK+dk]. grid = B*H*N = 8192, block = 64
__global__ void t_kernel(const float* __restrict__ Xq,
                         const float* __restrict__ Ek,
                         float* __restrict__ T) {
    int x = blockIdx.x;            // bh*N + i
    int bh = x >> 8;
    int h = bh & 7;
    int tid = threadIdx.x;         // r
    __shared__ float xq[32];
    if (tid < 32) xq[tid] = Xq[x * 32 + tid];
    __syncthreads();
    const float* ek = Ek + tid * 256 + h * 32;
    float acc = 0.f;
    for (int d = 0; d < 32; ++d) acc += ek[d] * xq[d];
    T[x * 64 + tid] = acc;
}

// attn scores + mask + softmax -> alpha. grid = B*H*N = 8192, block = 256 (j)
__global__ void attn_kernel(const float* __restrict__ Xq,
                            const float* __restrict__ Xk,
                            const float* __restrict__ T,
                            const int* __restrict__ mask,
                            const float* __restrict__ link,
                            float* __restrict__ alpha) {
    int x = blockIdx.x;            // bh*N + i
    int i = x & 255;
    int bh = x >> 8;
    int b = bh >> 3;
    int tid = threadIdx.x;         // j
    __shared__ float xq[32];
    __shared__ float tr[64];
    __shared__ float red[256];
    if (tid < 32) xq[tid] = Xq[x * 32 + tid];
    if (tid < 64) tr[tid] = T[x * 64 + tid];
    __syncthreads();
    int j = tid;
    const float* xk = Xk + (bh * 256 + j) * 32;
    float dot = 0.f;
    for (int d = 0; d < 32; ++d) dot += xq[d] * xk[d];
    const float* lk = link + ((b * 256 + i) * 256 + j) * 64;
    float bias = 0.f;
    for (int r = 0; r < 64; ++r) bias += lk[r] * tr[r];
    float s = (dot + bias) * SCALE_;
    if (mask[(b * 256 + i) * 256 + j] == 0) s = -1e9f;
    // softmax over j (block-wide)
    red[tid] = s;
    __syncthreads();
    for (int st = 128; st > 0; st >>= 1) {
        if (tid < st) red[tid] = fmaxf(red[tid], red[tid + st]);
        __syncthreads();
    }
    float m = red[0];
    __syncthreads();
    float e = expf(s - m);
    red[tid] = e;
    __syncthreads();
    for (int st = 128; st > 0; st >>= 1) {
        if (tid < st) red[tid] += red[tid + st];
        __syncthreads();
    }
    float inv = 1.f / red[0];
    alpha[x * 256 + j] = e * inv;
}

// S[b,h,i,r] = sum_j alpha[b,h,i,j] * link[b,i,j,r]. grid = 8192, block = 64 (r)
__global__ void s_kernel(const float* __restrict__ alpha,
                         const float* __restrict__ link,
                         float* __restrict__ S) {
    int x = blockIdx.x;            // bh*N + i
    int i = x & 255;
    int bh = x >> 8;
    int b = bh >> 3;
    int tid = threadIdx.x;         // r
    __shared__ float ar[256];
    for (int t = tid; t < 256; t += 64) ar[t] = alpha[x * 256 + t];
    __syncthreads();
    const float* lk = link + (b * 256 + i) * 256 * 64;
    float acc = 0.f;
    for (int j = 0; j < 256; ++j) acc += ar[j] * lk[j * 64 + tid];
    S[x * 64 + tid] = acc;
}

// Z[b,h,i,dv] = sum_j alpha*Xv + sum_r S*Ev. grid = 8192, block = 256
__global__ void z_kernel(const float* __restrict__ alpha,
                         const float* __restrict__ Xv,
                         const float* __restrict__ S,
                         const float* __restrict__ Ev,
                         float* __restrict__ Z) {
    int x = blockIdx.x;            // bh*N + i
    int bh = x >> 8;
    int h = bh & 7;
    int tid = threadIdx.x;
    __shared__ float ar[256];
    __shared__ float sr[64];
    __shared__ float part[256];
    ar[tid] = alpha[x * 256 + tid];
    if (tid < 64) sr[tid] = S[x * 64 + tid];
    __syncthreads();
    int dv = tid & 31, jc = tid >> 5;
    const float* xv = Xv + (bh * 256 + jc * 32) * 32;
    float acc = 0.f;
    for (int jj = 0; jj < 32; ++jj) acc += ar[jc * 32 + jj] * xv[jj * 32 + dv];
    part[tid] = acc;
    __syncthreads();
    if (tid < 32) {
        float z = 0.f;
        for (int c = 0; c < 8; ++c) z += part[c * 32 + tid];
        float rb = 0.f;
        for (int r = 0; r < 64; ++r) rb += sr[r] * Ev[r * 256 + h * 32 + tid];
        Z[x * 32 + tid] = z + rb;
    }
}

// out = Z_reshaped @ Wo + residual, then LayerNorm. grid = B*N = 1024, block = 256
__global__ void out_kernel(const float* __restrict__ Z,
                           const float* __restrict__ Wo,
                           const float* __restrict__ q,
                           const float* __restrict__ gamma,
                           const float* __restrict__ beta,
                           float* __restrict__ out) {
    int bn = blockIdx.x;           // b*N + i
    int b = bn >> 8, i = bn & 255;
    int tid = threadIdx.x;
    __shared__ float zr[256];
    __shared__ float red[256];
    int h = tid >> 5, dv = tid & 31;
    zr[tid] = Z[((b * 8 + h) * 256 + i) * 32 + dv];
    __syncthreads();
    float acc = q[bn * 256 + tid];
    for (int d = 0; d < 256; ++d) acc += zr[d] * Wo[d * 256 + tid];
    red[tid] = acc;
    __syncthreads();
    for (int st = 128; st > 0; st >>= 1) {
        if (tid < st) red[tid] += red[tid + st];
        __syncthreads();
    }
    float mu = red[0] * (1.f / 256.f);
    __syncthreads();
    float dev = acc - mu;
    red[tid] = dev * dev;
    __syncthreads();
    for (int st = 128; st > 0; st >>= 1) {
        if (tid < st) red[tid] += red[tid + st];
        __syncthreads();
    }
    float var = red[0] * (1.f / 256.f);
    out[bn * 256 + tid] = dev * rsqrtf(var + EPS_) * gamma[tid] + beta[tid];
}

extern "C" void kernel_launch(void* const* d_in, const int* in_sizes, int n_in,
                              void* d_out, int out_size, void* d_ws, size_t ws_size,
                              hipStream_t stream) {
    const float* q     = (const float*)d_in[0];
    // d_in[1] (k) and d_in[2] (v) are unused in this reference branch.
    const int*   mask  = (const int*)d_in[3];
    const float* link  = (const float*)d_in[4];
    const float* Wq    = (const float*)d_in[5];
    const float* Wk    = (const float*)d_in[6];
    const float* Wr    = (const float*)d_in[7];
    const float* Wv    = (const float*)d_in[8];
    const float* Wvv   = (const float*)d_in[9];
    const float* relE  = (const float*)d_in[10];
    const float* Wo    = (const float*)d_in[11];
    const float* gamma = (const float*)d_in[12];
    const float* beta  = (const float*)d_in[13];

    float* out   = (float*)d_out;
    float* alpha = out + B_ * N_ * D_;           // 262144 offset, [B,H,N,N]

    float* ws = (float*)d_ws;
    float* Ek = ws;                 // 64*256   = 16384
    float* Ev = Ek + 64 * 256;      // 16384
    float* Xq = Ev + 64 * 256;      // 262144
    float* Xk = Xq + 262144;        // 262144
    float* Xv = Xk + 262144;        // 262144
    float* T  = Xv + 262144;        // 524288
    float* S  = T  + 524288;        // 524288
    float* Z  = S  + 524288;        // 262144   total ~8.5 MB

    ek_ev_kernel<<<128, 256, 0, stream>>>(relE, Wr, Wvv, Ek, Ev);
    proj_kernel<<<B_ * N_, 256, 0, stream>>>(q, Wq, Wk, Wv, Xq, Xk, Xv);
    t_kernel<<<B_ * H_ * N_, 64, 0, stream>>>(Xq, Ek, T);
    attn_kernel<<<B_ * H_ * N_, 256, 0, stream>>>(Xq, Xk, T, mask, link, alpha);
    s_kernel<<<B_ * H_ * N_, 64, 0, stream>>>(alpha, link, S);
    z_kernel<<<B_ * H_ * N_, 256, 0, stream>>>(alpha, Xv, S, Ev, Z);
    out_kernel<<<B_ * N_, 256, 0, stream>>>(Z, Wo, q, gamma, beta, out);
}

// Round 2
// 302.956 us; speedup vs baseline: 1.0611x; 1.0611x over previous
//
#include <hip/hip_runtime.h>
#include <math.h>

// B=4, N=256, D=256, H=8, DK=32, DV=32, R=64
constexpr int B_ = 4, N_ = 256, D_ = 256, H_ = 8, DK_ = 32, DV_ = 32, R_ = 64;
constexpr float SCALE_ = 0.17677669529663687f;  // 1/sqrt(32)
constexpr float EPS_ = 1e-6f;

// Ek = relationE @ Wr, Ev = relationE @ Wvv   ([64,256] @ [256,256] each)
// grid = 128 (64 rows x 2 outputs), block = 256
__global__ void ek_ev_kernel(const float* __restrict__ relE,
                             const float* __restrict__ Wr,
                             const float* __restrict__ Wvv,
                             float* __restrict__ Ek, float* __restrict__ Ev) {
    int r = blockIdx.x & 63;
    int which = blockIdx.x >> 6;
    const float* W = which ? Wvv : Wr;
    float* out = which ? Ev : Ek;
    __shared__ float row[256];
    int tid = threadIdx.x;
    row[tid] = relE[r * 256 + tid];
    __syncthreads();
    float acc = 0.f;
    for (int d = 0; d < 256; ++d) acc += row[d] * W[d * 256 + tid];
    out[r * 256 + tid] = acc;
}

// Xq/Xk/Xv projections, [b,h,n,dk] layout. TILE=4 rows per block.
// grid = B*N/4 = 256, block = 256
__global__ void proj_kernel(const float* __restrict__ q,
                            const float* __restrict__ Wq,
                            const float* __restrict__ Wk,
                            const float* __restrict__ Wv,
                            float* __restrict__ Xq, float* __restrict__ Xk,
                            float* __restrict__ Xv) {
    int blk = blockIdx.x;          // rows blk*4 .. blk*4+3 (global bn index)
    int tid = threadIdx.x;
    __shared__ float rows[4][256];
    for (int t = tid; t < 1024; t += 256)
        rows[t >> 8][t & 255] = q[blk * 1024 + t];
    __syncthreads();
    float aq[4] = {0.f, 0.f, 0.f, 0.f};
    float ak[4] = {0.f, 0.f, 0.f, 0.f};
    float av[4] = {0.f, 0.f, 0.f, 0.f};
    for (int d = 0; d < 256; ++d) {
        float wq = Wq[d * 256 + tid];
        float wk = Wk[d * 256 + tid];
        float wv = Wv[d * 256 + tid];
#pragma unroll
        for (int rr = 0; rr < 4; ++rr) {
            float x = rows[rr][d];
            aq[rr] += x * wq;
            ak[rr] += x * wk;
            av[rr] += x * wv;
        }
    }
    int h = tid >> 5, dk = tid & 31;
#pragma unroll
    for (int rr = 0; rr < 4; ++rr) {
        int bn = blk * 4 + rr;
        int b = bn >> 8, n = bn & 255;
        int idx = ((b * H_ + h) * N_ + n) * 32 + dk;
        Xq[idx] = aq[rr];
        Xk[idx] = ak[rr];
        Xv[idx] = av[rr];
    }
}

// Fused: T (in LDS) + relation bias + QK dot + mask + softmax -> alpha.
// grid = B*N = 1024 (one block per (b,i)), block = 256 (thread = j)
__global__ void alpha_kernel(const float* __restrict__ Xq,
                             const float* __restrict__ Xk,
                             const float* __restrict__ Ek,
                             const int* __restrict__ mask,
                             const float* __restrict__ link,
                             float* __restrict__ alpha) {
    int bi = blockIdx.x;
    int b = bi >> 8, i = bi & 255;
    int tid = threadIdx.x;
    __shared__ float Xqsh[256];    // [h][d]
    __shared__ float Tsh[512];     // [h][r]
    __shared__ float redsh[64];    // [h][wave] reduce scratch

    {   // load Xq[b,:,i,:]
        int h = tid >> 5, d = tid & 31;
        Xqsh[tid] = Xq[((b * H_ + h) * N_ + i) * 32 + d];
    }
    __syncthreads();

    // T[h][r] = Xq[b,h,i,:] . Ek[r, h*32:(h+1)*32]
    for (int idx = tid; idx < 512; idx += 256) {
        int h = idx >> 6, r = idx & 63;
        const float4* ek4 = (const float4*)(Ek + r * 256 + h * 32);
        const float4* xq4 = (const float4*)(Xqsh + h * 32);
        float acc = 0.f;
#pragma unroll
        for (int d4 = 0; d4 < 8; ++d4) {
            float4 e = ek4[d4], x = xq4[d4];
            acc += e.x * x.x + e.y * x.y + e.z * x.z + e.w * x.w;
        }
        Tsh[idx] = acc;
    }
    __syncthreads();

    int j = tid;
    float s[8];
#pragma unroll
    for (int h = 0; h < 8; ++h) s[h] = 0.f;

    // relation bias: s[h] += sum_r link[b,i,j,r] * T[h][r]
    {
        const float4* lp = (const float4*)(link + (((size_t)(b * 256 + i) * 256 + j) * 64));
#pragma unroll
        for (int r4 = 0; r4 < 16; ++r4) {
            float4 lv = lp[r4];
#pragma unroll
            for (int h = 0; h < 8; ++h) {
                float4 t = *(const float4*)(Tsh + h * 64 + r4 * 4);
                s[h] += lv.x * t.x + lv.y * t.y + lv.z * t.z + lv.w * t.w;
            }
        }
    }

    // QK dot
#pragma unroll
    for (int h = 0; h < 8; ++h) {
        const float4* xk4 = (const float4*)(Xk + ((size_t)((b * H_ + h) * N_ + j)) * 32);
        const float4* xq4 = (const float4*)(Xqsh + h * 32);
        float d = 0.f;
#pragma unroll
        for (int d4 = 0; d4 < 8; ++d4) {
            float4 a = xk4[d4], c = xq4[d4];
            d += a.x * c.x + a.y * c.y + a.z * c.z + a.w * c.w;
        }
        s[h] = (s[h] + d) * SCALE_;
    }

    int mk = mask[(b * 256 + i) * 256 + j];
    if (mk == 0) {
#pragma unroll
        for (int h = 0; h < 8; ++h) s[h] = -1e9f;
    }

    // softmax over j (block = 4 waves of 64)
    int lane = tid & 63, wv = tid >> 6;
#pragma unroll
    for (int h = 0; h < 8; ++h) {
        float v = s[h];
        for (int off = 32; off > 0; off >>= 1) v = fmaxf(v, __shfl_xor(v, off));
        if (lane == 0) redsh[h * 4 + wv] = v;
    }
    __syncthreads();
    float mx[8];
#pragma unroll
    for (int h = 0; h < 8; ++h)
        mx[h] = fmaxf(fmaxf(redsh[h * 4 + 0], redsh[h * 4 + 1]),
                      fmaxf(redsh[h * 4 + 2], redsh[h * 4 + 3]));
    __syncthreads();
#pragma unroll
    for (int h = 0; h < 8; ++h) {
        float e = __expf(s[h] - mx[h]);
        s[h] = e;
        float v = e;
        for (int off = 32; off > 0; off >>= 1) v += __shfl_xor(v, off);
        if (lane == 0) redsh[h * 4 + wv] = v;
    }
    __syncthreads();
#pragma unroll
    for (int h = 0; h < 8; ++h) {
        float esum = redsh[h * 4 + 0] + redsh[h * 4 + 1] +
                     redsh[h * 4 + 2] + redsh[h * 4 + 3];
        alpha[(((size_t)(b * H_ + h) * N_ + i)) * 256 + j] = s[h] / esum;
    }
}

// Fused S + Z. grid = B*N = 1024 (one block per (b,i)), block = 256
// S[h][r] = sum_j alpha[h][j] * link[b,i,j,r]   (link read coalesced: lane = r)
// Z[h][dv] = sum_j alpha[h][j]*Xv[b,h,j,dv] + sum_r S[h][r]*Ev[r, h*32+dv]
__global__ void sz_kernel(const float* __restrict__ alpha,
                          const float* __restrict__ link,
                          const float* __restrict__ Xv,
                          const float* __restrict__ Ev,
                          float* __restrict__ Z) {
    int bi = blockIdx.x;
    int b = bi >> 8, i = bi & 255;
    int tid = threadIdx.x;
    __shared__ float ash[2048];    // [h][j] 8 KB
    __shared__ float part[2048];   // [g][h][r] 8 KB
    __shared__ float Ssh[512];     // [h][r] 2 KB

    for (int t = tid; t < 2048; t += 256) {
        int h = t >> 8, jj = t & 255;
        ash[t] = alpha[(((size_t)(b * H_ + h) * N_ + i)) * 256 + jj];
    }
    __syncthreads();

    int r = tid & 63, g = tid >> 6;   // wave g handles j in [g*64, g*64+64)
    float pacc[8] = {0.f, 0.f, 0.f, 0.f, 0.f, 0.f, 0.f, 0.f};
    const float* lp = link + ((size_t)((b * 256 + i) * 256 + g * 64)) * 64 + r;
#pragma unroll 4
    for (int j4 = 0; j4 < 16; ++j4) {
        float l0 = lp[(j4 * 4 + 0) * 64];
        float l1 = lp[(j4 * 4 + 1) * 64];
        float l2 = lp[(j4 * 4 + 2) * 64];
        float l3 = lp[(j4 * 4 + 3) * 64];
#pragma unroll
        for (int h = 0; h < 8; ++h) {
            float4 a = *(const float4*)(ash + h * 256 + g * 64 + j4 * 4);
            pacc[h] += a.x * l0 + a.y * l1 + a.z * l2 + a.w * l3;
        }
    }
#pragma unroll
    for (int h = 0; h < 8; ++h) part[(g * 8 + h) * 64 + r] = pacc[h];
    __syncthreads();
    for (int idx = tid; idx < 512; idx += 256)
        Ssh[idx] = part[idx] + part[512 + idx] + part[1024 + idx] + part[1536 + idx];
    __syncthreads();

    // Z
    int h = tid >> 5, dv = tid & 31;
    float z = 0.f;
    const float* xv = Xv + ((size_t)(b * H_ + h) * N_) * 32 + dv;
#pragma unroll 8
    for (int j4 = 0; j4 < 64; ++j4) {
        float4 a = *(const float4*)(ash + h * 256 + j4 * 4);
        z += a.x * xv[(j4 * 4 + 0) * 32] + a.y * xv[(j4 * 4 + 1) * 32] +
             a.z * xv[(j4 * 4 + 2) * 32] + a.w * xv[(j4 * 4 + 3) * 32];
    }
#pragma unroll
    for (int r4 = 0; r4 < 16; ++r4) {
        float4 sv = *(const float4*)(Ssh + h * 64 + r4 * 4);
        z += sv.x * Ev[(r4 * 4 + 0) * 256 + h * 32 + dv] +
             sv.y * Ev[(r4 * 4 + 1) * 256 + h * 32 + dv] +
             sv.z * Ev[(r4 * 4 + 2) * 256 + h * 32 + dv] +
             sv.w * Ev[(r4 * 4 + 3) * 256 + h * 32 + dv];
    }
    Z[(((size_t)(b * H_ + h) * N_ + i)) * 32 + dv] = z;
}

// out = Z_reshaped @ Wo + residual, then LayerNorm. TILE=4 rows per block.
// grid = 256, block = 256
__global__ void out_kernel(const float* __restrict__ Z,
                           const float* __restrict__ Wo,
                           const float* __restrict__ q,
                           const float* __restrict__ gamma,
                           const float* __restrict__ beta,
                           float* __restrict__ out) {
    int blk = blockIdx.x;
    int tid = threadIdx.x;
    __shared__ float zr[4][256];
    __shared__ float redsh[32];
    for (int t = tid; t < 1024; t += 256) {
        int rr = t >> 8, d = t & 255;
        int h = d >> 5, dv = d & 31;
        int bn = blk * 4 + rr;
        int b = bn >> 8, i = bn & 255;
        zr[rr][d] = Z[((b * H_ + h) * N_ + i) * 32 + dv];
    }
    __syncthreads();
    float acc[4];
#pragma unroll
    for (int rr = 0; rr < 4; ++rr) acc[rr] = q[(blk * 4 + rr) * 256 + tid];
    for (int d = 0; d < 256; ++d) {
        float w = Wo[d * 256 + tid];
#pragma unroll
        for (int rr = 0; rr < 4; ++rr) acc[rr] += zr[rr][d] * w;
    }
    // LayerNorm per row (block-wide reduce of sum and sumsq)
    int lane = tid & 63, wv = tid >> 6;
#pragma unroll
    for (int rr = 0; rr < 4; ++rr) {
        float v = acc[rr], v2 = acc[rr] * acc[rr];
        for (int off = 32; off > 0; off >>= 1) {
            v += __shfl_xor(v, off);
            v2 += __shfl_xor(v2, off);
        }
        if (lane == 0) {
            redsh[rr * 8 + wv] = v;
            redsh[rr * 8 + 4 + wv] = v2;
        }
    }
    __syncthreads();
#pragma unroll
    for (int rr = 0; rr < 4; ++rr) {
        float sum = redsh[rr * 8 + 0] + redsh[rr * 8 + 1] + redsh[rr * 8 + 2] + redsh[rr * 8 + 3];
        float sum2 = redsh[rr * 8 + 4] + redsh[rr * 8 + 5] + redsh[rr * 8 + 6] + redsh[rr * 8 + 7];
        float mu = sum * (1.f / 256.f);
        float var = sum2 * (1.f / 256.f) - mu * mu;
        float dev = acc[rr] - mu;
        out[(blk * 4 + rr) * 256 + tid] = dev * rsqrtf(var + EPS_) * gamma[tid] + beta[tid];
    }
}

extern "C" void kernel_launch(void* const* d_in, const int* in_sizes, int n_in,
                              void* d_out, int out_size, void* d_ws, size_t ws_size,
                              hipStream_t stream) {
    const float* q     = (const float*)d_in[0];
    const int*   mask  = (const int*)d_in[3];
    const float* link  = (const float*)d_in[4];
    const float* Wq    = (const float*)d_in[5];
    const float* Wk    = (const float*)d_in[6];
    const float* Wr    = (const float*)d_in[7];
    const float* Wv    = (const float*)d_in[8];
    const float* Wvv   = (const float*)d_in[9];
    const float* relE  = (const float*)d_in[10];
    const float* Wo    = (const float*)d_in[11];
    const float* gamma = (const float*)d_in[12];
    const float* beta  = (const float*)d_in[13];

    float* out   = (float*)d_out;
    float* alpha = out + B_ * N_ * D_;      // second output, [B,H,N,N]

    float* ws = (float*)d_ws;
    float* Ek = ws;                 // 16384
    float* Ev = Ek + 16384;         // 16384
    float* Xq = Ev + 16384;         // 262144
    float* Xk = Xq + 262144;        // 262144
    float* Xv = Xk + 262144;        // 262144
    float* Z  = Xv + 262144;        // 262144

    ek_ev_kernel<<<128, 256, 0, stream>>>(relE, Wr, Wvv, Ek, Ev);
    proj_kernel<<<256, 256, 0, stream>>>(q, Wq, Wk, Wv, Xq, Xk, Xv);
    alpha_kernel<<<1024, 256, 0, stream>>>(Xq, Xk, Ek, mask, link, alpha);
    sz_kernel<<<1024, 256, 0, stream>>>(alpha, link, Xv, Ev, Z);
    out_kernel<<<256, 256, 0, stream>>>(Z, Wo, q, gamma, beta, out);
}

// Round 3
// 234.056 us; speedup vs baseline: 1.3735x; 1.2944x over previous
//
#include <hip/hip_runtime.h>
#include <math.h>

// B=4, N=256, D=256, H=8, DK=32, DV=32, R=64
constexpr int B_ = 4, N_ = 256, D_ = 256, H_ = 8, DK_ = 32, DV_ = 32, R_ = 64;
constexpr float SCALE_ = 0.17677669529663687f;  // 1/sqrt(32)
constexpr float EPS_ = 1e-6f;

// Ek = relationE @ Wr, Ev = relationE @ Wvv   ([64,256] @ [256,256] each)
// grid = 128 (64 rows x 2 outputs), block = 256
__global__ __launch_bounds__(256) void ek_ev_kernel(
        const float* __restrict__ relE,
        const float* __restrict__ Wr,
        const float* __restrict__ Wvv,
        float* __restrict__ Ek, float* __restrict__ Ev) {
    int r = blockIdx.x & 63;
    int which = blockIdx.x >> 6;
    const float* W = which ? Wvv : Wr;
    float* out = which ? Ev : Ek;
    __shared__ float row[256];
    int tid = threadIdx.x;
    row[tid] = relE[r * 256 + tid];
    __syncthreads();
    float acc = 0.f;
    for (int d = 0; d < 256; ++d) acc += row[d] * W[d * 256 + tid];
    out[r * 256 + tid] = acc;
}

// Xq/Xk/Xv projections, [b,h,n,dk] layout. TILE=4 rows per block.
// grid = B*N/4 = 256, block = 256
__global__ __launch_bounds__(256) void proj_kernel(
        const float* __restrict__ q,
        const float* __restrict__ Wq,
        const float* __restrict__ Wk,
        const float* __restrict__ Wv,
        float* __restrict__ Xq, float* __restrict__ Xk,
        float* __restrict__ Xv) {
    int blk = blockIdx.x;          // rows blk*4 .. blk*4+3 (global bn index)
    int tid = threadIdx.x;
    __shared__ float rows[4][256];
    for (int t = tid; t < 1024; t += 256)
        rows[t >> 8][t & 255] = q[blk * 1024 + t];
    __syncthreads();
    float aq[4] = {0.f, 0.f, 0.f, 0.f};
    float ak[4] = {0.f, 0.f, 0.f, 0.f};
    float av[4] = {0.f, 0.f, 0.f, 0.f};
    for (int d = 0; d < 256; ++d) {
        float wq = Wq[d * 256 + tid];
        float wk = Wk[d * 256 + tid];
        float wv = Wv[d * 256 + tid];
#pragma unroll
        for (int rr = 0; rr < 4; ++rr) {
            float x = rows[rr][d];
            aq[rr] += x * wq;
            ak[rr] += x * wk;
            av[rr] += x * wv;
        }
    }
    int h = tid >> 5, dk = tid & 31;
#pragma unroll
    for (int rr = 0; rr < 4; ++rr) {
        int bn = blk * 4 + rr;
        int b = bn >> 8, n = bn & 255;
        int idx = ((b * H_ + h) * N_ + n) * 32 + dk;
        Xq[idx] = aq[rr];
        Xk[idx] = ak[rr];
        Xv[idx] = av[rr];
    }
}

// Fully fused attention core: T + relation bias + QK + mask + softmax ->
// alpha (global out + LDS), then S (link re-read, L2-hot) and Z, per (b,i).
// grid = B*N = 1024, block = 256
__global__ __launch_bounds__(256) void attn_fused_kernel(
        const float* __restrict__ Xq,
        const float* __restrict__ Xk,
        const float* __restrict__ Xv,
        const float* __restrict__ Ek,
        const float* __restrict__ Ev,
        const int* __restrict__ mask,
        const float* __restrict__ link,
        float* __restrict__ alpha,
        float* __restrict__ Z) {
    int bi = blockIdx.x;
    int b = bi >> 8, i = bi & 255;
    int tid = threadIdx.x;
    __shared__ float Xqsh[256];    // [h][d]    1 KB
    __shared__ float Tsh[512];     // [h][r]    2 KB
    __shared__ float redsh[64];    //           256 B
    __shared__ float ash[2048];    // [h][j]    8 KB
    __shared__ float part[2048];   // [g][h][r] 8 KB
    __shared__ float Ssh[512];     // [h][r]    2 KB

    {   // load Xq[b,:,i,:]
        int h = tid >> 5, d = tid & 31;
        Xqsh[tid] = Xq[((b * H_ + h) * N_ + i) * 32 + d];
    }
    __syncthreads();

    // T[h][r] = Xq[b,h,i,:] . Ek[r, h*32:(h+1)*32]
    for (int idx = tid; idx < 512; idx += 256) {
        int h = idx >> 6, r = idx & 63;
        const float4* ek4 = (const float4*)(Ek + r * 256 + h * 32);
        const float4* xq4 = (const float4*)(Xqsh + h * 32);
        float acc = 0.f;
#pragma unroll
        for (int d4 = 0; d4 < 8; ++d4) {
            float4 e = ek4[d4], x = xq4[d4];
            acc += e.x * x.x + e.y * x.y + e.z * x.z + e.w * x.w;
        }
        Tsh[idx] = acc;
    }
    __syncthreads();

    int j = tid;
    float s[8];
#pragma unroll
    for (int h = 0; h < 8; ++h) s[h] = 0.f;

    // relation bias: s[h] += sum_r link[b,i,j,r] * T[h][r]
    {
        const float4* lp = (const float4*)(link + (((size_t)(b * 256 + i) * 256 + j) * 64));
#pragma unroll
        for (int r4 = 0; r4 < 16; ++r4) {
            float4 lv = lp[r4];
#pragma unroll
            for (int h = 0; h < 8; ++h) {
                float4 t = *(const float4*)(Tsh + h * 64 + r4 * 4);
                s[h] += lv.x * t.x + lv.y * t.y + lv.z * t.z + lv.w * t.w;
            }
        }
    }

    // QK dot
#pragma unroll
    for (int h = 0; h < 8; ++h) {
        const float4* xk4 = (const float4*)(Xk + ((size_t)((b * H_ + h) * N_ + j)) * 32);
        const float4* xq4 = (const float4*)(Xqsh + h * 32);
        float d = 0.f;
#pragma unroll
        for (int d4 = 0; d4 < 8; ++d4) {
            float4 a = xk4[d4], c = xq4[d4];
            d += a.x * c.x + a.y * c.y + a.z * c.z + a.w * c.w;
        }
        s[h] = (s[h] + d) * SCALE_;
    }

    if (mask[(b * 256 + i) * 256 + j] == 0) {
#pragma unroll
        for (int h = 0; h < 8; ++h) s[h] = -1e9f;
    }

    // softmax over j (block = 4 waves of 64)
    int lane = tid & 63, wv = tid >> 6;
#pragma unroll
    for (int h = 0; h < 8; ++h) {
        float v = s[h];
        for (int off = 32; off > 0; off >>= 1) v = fmaxf(v, __shfl_xor(v, off));
        if (lane == 0) redsh[h * 4 + wv] = v;
    }
    __syncthreads();
    float mx[8];
#pragma unroll
    for (int h = 0; h < 8; ++h)
        mx[h] = fmaxf(fmaxf(redsh[h * 4 + 0], redsh[h * 4 + 1]),
                      fmaxf(redsh[h * 4 + 2], redsh[h * 4 + 3]));
    __syncthreads();
#pragma unroll
    for (int h = 0; h < 8; ++h) {
        float e = __expf(s[h] - mx[h]);
        s[h] = e;
        float v = e;
        for (int off = 32; off > 0; off >>= 1) v += __shfl_xor(v, off);
        if (lane == 0) redsh[h * 4 + wv] = v;
    }
    __syncthreads();
#pragma unroll
    for (int h = 0; h < 8; ++h) {
        float esum = redsh[h * 4 + 0] + redsh[h * 4 + 1] +
                     redsh[h * 4 + 2] + redsh[h * 4 + 3];
        float a = s[h] * (1.f / esum);
        alpha[(((size_t)(b * H_ + h) * N_ + i)) * 256 + j] = a;
        ash[h * 256 + j] = a;
    }
    __syncthreads();

    // S[h][r] = sum_j alpha[h][j] * link[b,i,j,r]  (link re-read: L2-hot)
    {
        int r = tid & 63, g = tid >> 6;  // wave g handles j in [g*64, (g+1)*64)
        float pacc[8] = {0.f, 0.f, 0.f, 0.f, 0.f, 0.f, 0.f, 0.f};
        const float* lp2 = link + ((size_t)((b * 256 + i) * 256 + g * 64)) * 64 + r;
#pragma unroll 4
        for (int j4 = 0; j4 < 16; ++j4) {
            float l0 = lp2[(j4 * 4 + 0) * 64];
            float l1 = lp2[(j4 * 4 + 1) * 64];
            float l2 = lp2[(j4 * 4 + 2) * 64];
            float l3 = lp2[(j4 * 4 + 3) * 64];
#pragma unroll
            for (int h = 0; h < 8; ++h) {
                float4 a = *(const float4*)(ash + h * 256 + g * 64 + j4 * 4);
                pacc[h] += a.x * l0 + a.y * l1 + a.z * l2 + a.w * l3;
            }
        }
#pragma unroll
        for (int h = 0; h < 8; ++h) part[(g * 8 + h) * 64 + r] = pacc[h];
    }
    __syncthreads();
    for (int idx = tid; idx < 512; idx += 256)
        Ssh[idx] = part[idx] + part[512 + idx] + part[1024 + idx] + part[1536 + idx];
    __syncthreads();

    // Z[h][dv] = sum_j alpha[h][j]*Xv[b,h,j,dv] + sum_r S[h][r]*Ev[r,h*32+dv]
    {
        int h = tid >> 5, dv = tid & 31;
        float z = 0.f;
        const float* xv = Xv + ((size_t)(b * H_ + h) * N_) * 32 + dv;
#pragma unroll 8
        for (int j4 = 0; j4 < 64; ++j4) {
            float4 a = *(const float4*)(ash + h * 256 + j4 * 4);
            z += a.x * xv[(j4 * 4 + 0) * 32] + a.y * xv[(j4 * 4 + 1) * 32] +
                 a.z * xv[(j4 * 4 + 2) * 32] + a.w * xv[(j4 * 4 + 3) * 32];
        }
#pragma unroll
        for (int r4 = 0; r4 < 16; ++r4) {
            float4 sv = *(const float4*)(Ssh + h * 64 + r4 * 4);
            z += sv.x * Ev[(r4 * 4 + 0) * 256 + h * 32 + dv] +
                 sv.y * Ev[(r4 * 4 + 1) * 256 + h * 32 + dv] +
                 sv.z * Ev[(r4 * 4 + 2) * 256 + h * 32 + dv] +
                 sv.w * Ev[(r4 * 4 + 3) * 256 + h * 32 + dv];
        }
        Z[(((size_t)(b * H_ + h) * N_ + i)) * 32 + dv] = z;
    }
}

// out = Z_reshaped @ Wo + residual, then LayerNorm. TILE=4 rows per block.
// grid = 256, block = 256
__global__ __launch_bounds__(256) void out_kernel(
        const float* __restrict__ Z,
        const float* __restrict__ Wo,
        const float* __restrict__ q,
        const float* __restrict__ gamma,
        const float* __restrict__ beta,
        float* __restrict__ out) {
    int blk = blockIdx.x;
    int tid = threadIdx.x;
    __shared__ float zr[4][256];
    __shared__ float redsh[32];
    for (int t = tid; t < 1024; t += 256) {
        int rr = t >> 8, d = t & 255;
        int h = d >> 5, dv = d & 31;
        int bn = blk * 4 + rr;
        int b = bn >> 8, i = bn & 255;
        zr[rr][d] = Z[((b * H_ + h) * N_ + i) * 32 + dv];
    }
    __syncthreads();
    float acc[4];
#pragma unroll
    for (int rr = 0; rr < 4; ++rr) acc[rr] = q[(blk * 4 + rr) * 256 + tid];
    for (int d = 0; d < 256; ++d) {
        float w = Wo[d * 256 + tid];
#pragma unroll
        for (int rr = 0; rr < 4; ++rr) acc[rr] += zr[rr][d] * w;
    }
    // LayerNorm per row (block-wide reduce of sum and sumsq)
    int lane = tid & 63, wv = tid >> 6;
#pragma unroll
    for (int rr = 0; rr < 4; ++rr) {
        float v = acc[rr], v2 = acc[rr] * acc[rr];
        for (int off = 32; off > 0; off >>= 1) {
            v += __shfl_xor(v, off);
            v2 += __shfl_xor(v2, off);
        }
        if (lane == 0) {
            redsh[rr * 8 + wv] = v;
            redsh[rr * 8 + 4 + wv] = v2;
        }
    }
    __syncthreads();
#pragma unroll
    for (int rr = 0; rr < 4; ++rr) {
        float sum = redsh[rr * 8 + 0] + redsh[rr * 8 + 1] + redsh[rr * 8 + 2] + redsh[rr * 8 + 3];
        float sum2 = redsh[rr * 8 + 4] + redsh[rr * 8 + 5] + redsh[rr * 8 + 6] + redsh[rr * 8 + 7];
        float mu = sum * (1.f / 256.f);
        float var = sum2 * (1.f / 256.f) - mu * mu;
        float dev = acc[rr] - mu;
        out[(blk * 4 + rr) * 256 + tid] = dev * rsqrtf(var + EPS_) * gamma[tid] + beta[tid];
    }
}

extern "C" void kernel_launch(void* const* d_in, const int* in_sizes, int n_in,
                              void* d_out, int out_size, void* d_ws, size_t ws_size,
                              hipStream_t stream) {
    const float* q     = (const float*)d_in[0];
    const int*   mask  = (const int*)d_in[3];
    const float* link  = (const float*)d_in[4];
    const float* Wq    = (const float*)d_in[5];
    const float* Wk    = (const float*)d_in[6];
    const float* Wr    = (const float*)d_in[7];
    const float* Wv    = (const float*)d_in[8];
    const float* Wvv   = (const float*)d_in[9];
    const float* relE  = (const float*)d_in[10];
    const float* Wo    = (const float*)d_in[11];
    const float* gamma = (const float*)d_in[12];
    const float* beta  = (const float*)d_in[13];

    float* out   = (float*)d_out;
    float* alpha = out + B_ * N_ * D_;      // second output, [B,H,N,N]

    float* ws = (float*)d_ws;
    float* Ek = ws;                 // 16384
    float* Ev = Ek + 16384;         // 16384
    float* Xq = Ev + 16384;         // 262144
    float* Xk = Xq + 262144;        // 262144
    float* Xv = Xk + 262144;        // 262144
    float* Z  = Xv + 262144;        // 262144

    ek_ev_kernel<<<128, 256, 0, stream>>>(relE, Wr, Wvv, Ek, Ev);
    proj_kernel<<<256, 256, 0, stream>>>(q, Wq, Wk, Wv, Xq, Xk, Xv);
    attn_fused_kernel<<<1024, 256, 0, stream>>>(Xq, Xk, Xv, Ek, Ev, mask, link,
                                                alpha, Z);
    out_kernel<<<256, 256, 0, stream>>>(Z, Wo, q, gamma, beta, out);
}

// Round 4
// 229.489 us; speedup vs baseline: 1.4008x; 1.0199x over previous
//
#include <hip/hip_runtime.h>
#include <math.h>

// B=4, N=256, D=256, H=8, DK=32, DV=32, R=64
constexpr int B_ = 4, N_ = 256, D_ = 256, H_ = 8, DK_ = 32, DV_ = 32, R_ = 64;
constexpr float SCALE_ = 0.17677669529663687f;  // 1/sqrt(32)
constexpr float EPS_ = 1e-6f;

// ---------------------------------------------------------------------------
// K1: Ek = relationE @ Wr, Ev = relationE @ Wvv   ([64,256] @ [256,256])
// grid = 128 (64 rows x 2 outputs), block = 256
__global__ __launch_bounds__(256) void ekev_kernel(
        const float* __restrict__ relE, const float* __restrict__ Wr,
        const float* __restrict__ Wvv, float* __restrict__ Ek,
        float* __restrict__ Ev) {
    int r = blockIdx.x & 63;
    int which = blockIdx.x >> 6;
    const float* W = which ? Wvv : Wr;
    float* out = which ? Ev : Ek;
    __shared__ float row[256];
    int tid = threadIdx.x;
    row[tid] = relE[r * 256 + tid];
    __syncthreads();
    float acc = 0.f;
    for (int d = 0; d < 256; ++d) acc += row[d] * W[d * 256 + tid];
    out[r * 256 + tid] = acc;
}

// ---------------------------------------------------------------------------
// K2: Mcat[d, h*64+r] = sum_dk Wq[d, h*32+dk] * Ek[r, h*32+dk]
// grid = 256 (one block per d), block = 256
__global__ __launch_bounds__(256) void mcat_kernel(
        const float* __restrict__ Wq, const float* __restrict__ Ek,
        float* __restrict__ M) {
    int d = blockIdx.x;
    int t = threadIdx.x;
    __shared__ float wrow[256];
    wrow[t] = Wq[d * 256 + t];
    __syncthreads();
    for (int hr = t; hr < 512; hr += 256) {
        int h = hr >> 6, r = hr & 63;
        const float4* ek4 = (const float4*)(Ek + r * 256 + h * 32);
        const float4* w4 = (const float4*)(wrow + h * 32);
        float acc = 0.f;
#pragma unroll
        for (int k = 0; k < 8; ++k) {
            float4 e = ek4[k], w = w4[k];
            acc += e.x * w.x + e.y * w.y + e.z * w.z + e.w * w.w;
        }
        M[d * 512 + hr] = acc;
    }
}

// ---------------------------------------------------------------------------
// K3: fused projection GEMM: [1024 rows x 1280 cols] = q[1024,256] @ cat(Wq,Wk,Wv,Mcat)
// Outputs Xq/Xk/Xv in [b,h,n,dk] layout and T[bi][h*64+r].
// grid = 32 rowtiles * 20 coltiles = 640, block = 256, 8 outputs/thread
__global__ __launch_bounds__(256) void projT_kernel(
        const float* __restrict__ q, const float* __restrict__ Wq,
        const float* __restrict__ Wk, const float* __restrict__ Wv,
        const float* __restrict__ M, float* __restrict__ Xq,
        float* __restrict__ Xk, float* __restrict__ Xv,
        float* __restrict__ T) {
    int rt = blockIdx.x / 20, ct = blockIdx.x % 20;
    int t = threadIdx.x;
    __shared__ float qsh[32 * 256];  // 32 KB
    {
        const float4* qb = (const float4*)(q + rt * 32 * 256);
        float4* qs = (float4*)qsh;
#pragma unroll
        for (int k = 0; k < 8; ++k) qs[t + k * 256] = qb[t + k * 256];
    }
    __syncthreads();
    int c = t & 63, rg = t >> 6;
    const float* W;
    int ncols, ccol;
    if (ct < 4)       { W = Wq; ccol = ct * 64 + c;        ncols = 256; }
    else if (ct < 8)  { W = Wk; ccol = (ct - 4) * 64 + c;  ncols = 256; }
    else if (ct < 12) { W = Wv; ccol = (ct - 8) * 64 + c;  ncols = 256; }
    else              { W = M;  ccol = (ct - 12) * 64 + c; ncols = 512; }
    float acc[8] = {0.f, 0.f, 0.f, 0.f, 0.f, 0.f, 0.f, 0.f};
    for (int d4 = 0; d4 < 64; ++d4) {
        float w0 = W[(d4 * 4 + 0) * ncols + ccol];
        float w1 = W[(d4 * 4 + 1) * ncols + ccol];
        float w2 = W[(d4 * 4 + 2) * ncols + ccol];
        float w3 = W[(d4 * 4 + 3) * ncols + ccol];
#pragma unroll
        for (int ii = 0; ii < 8; ++ii) {
            float4 qv = *(const float4*)(qsh + (rg * 8 + ii) * 256 + d4 * 4);
            acc[ii] += qv.x * w0 + qv.y * w1 + qv.z * w2 + qv.w * w3;
        }
    }
#pragma unroll
    for (int ii = 0; ii < 8; ++ii) {
        int row = rt * 32 + rg * 8 + ii;
        int b = row >> 8, n = row & 255;
        if (ct < 12) {
            int h = ccol >> 5, dk = ccol & 31;
            float* dst = (ct < 4) ? Xq : (ct < 8) ? Xk : Xv;
            dst[((b * 8 + h) * 256 + n) * 32 + dk] = acc[ii];
        } else {
            T[(size_t)row * 512 + ccol] = acc[ii];
        }
    }
}

// ---------------------------------------------------------------------------
// K4: qk[b,h,i,j] = Xq[b,h,i,:].Xk[b,h,j,:]  — batched tiled GEMM, K=32
// grid = 32 bh * 4 itiles * 4 jtiles = 512, block = 256 (16x16), 4x4 outs
__global__ __launch_bounds__(256) void qk_kernel(
        const float* __restrict__ Xq, const float* __restrict__ Xk,
        float* __restrict__ qk) {
    int x = blockIdx.x;
    int jt = x & 3, it = (x >> 2) & 3, bh = x >> 4;
    int t = threadIdx.x;
    __shared__ float xqsh[32 * 64];  // [dk][i] 8 KB
    __shared__ float xksh[32 * 64];  // [dk][j] 8 KB
#pragma unroll
    for (int k = 0; k < 2; ++k) {
        int m = t + k * 256;  // f4 index 0..511
        int i = m >> 3, dq4 = m & 7;
        float4 v = *(const float4*)(Xq + ((size_t)(bh * 256 + it * 64 + i)) * 32 + dq4 * 4);
        xqsh[(dq4 * 4 + 0) * 64 + i] = v.x;
        xqsh[(dq4 * 4 + 1) * 64 + i] = v.y;
        xqsh[(dq4 * 4 + 2) * 64 + i] = v.z;
        xqsh[(dq4 * 4 + 3) * 64 + i] = v.w;
        float4 u = *(const float4*)(Xk + ((size_t)(bh * 256 + jt * 64 + i)) * 32 + dq4 * 4);
        xksh[(dq4 * 4 + 0) * 64 + i] = u.x;
        xksh[(dq4 * 4 + 1) * 64 + i] = u.y;
        xksh[(dq4 * 4 + 2) * 64 + i] = u.z;
        xksh[(dq4 * 4 + 3) * 64 + i] = u.w;
    }
    __syncthreads();
    int ti = t >> 4, tj = t & 15;
    float acc[4][4];
#pragma unroll
    for (int a = 0; a < 4; ++a)
#pragma unroll
        for (int bb = 0; bb < 4; ++bb) acc[a][bb] = 0.f;
    for (int dk = 0; dk < 32; ++dk) {
        float xa0 = xqsh[dk * 64 + ti * 4 + 0];
        float xa1 = xqsh[dk * 64 + ti * 4 + 1];
        float xa2 = xqsh[dk * 64 + ti * 4 + 2];
        float xa3 = xqsh[dk * 64 + ti * 4 + 3];
        float xb0 = xksh[dk * 64 + tj * 4 + 0];
        float xb1 = xksh[dk * 64 + tj * 4 + 1];
        float xb2 = xksh[dk * 64 + tj * 4 + 2];
        float xb3 = xksh[dk * 64 + tj * 4 + 3];
        acc[0][0] += xa0 * xb0; acc[0][1] += xa0 * xb1; acc[0][2] += xa0 * xb2; acc[0][3] += xa0 * xb3;
        acc[1][0] += xa1 * xb0; acc[1][1] += xa1 * xb1; acc[1][2] += xa1 * xb2; acc[1][3] += xa1 * xb3;
        acc[2][0] += xa2 * xb0; acc[2][1] += xa2 * xb1; acc[2][2] += xa2 * xb2; acc[2][3] += xa2 * xb3;
        acc[3][0] += xa3 * xb0; acc[3][1] += xa3 * xb1; acc[3][2] += xa3 * xb2; acc[3][3] += xa3 * xb3;
    }
#pragma unroll
    for (int a = 0; a < 4; ++a) {
        int i = it * 64 + ti * 4 + a;
        float4 v = make_float4(acc[a][0], acc[a][1], acc[a][2], acc[a][3]);
        *(float4*)(qk + ((size_t)(bh * 256 + i)) * 256 + jt * 64 + tj * 4) = v;
    }
}

// ---------------------------------------------------------------------------
// K5: bias[b,h,i,j] = sum_r link[b,i,j,r] * T[bi][h*64+r]   (written to alpha slot)
// grid = 4096 (bi*4 + jt of 64 j), block = 256
__global__ __launch_bounds__(256) void bias_kernel(
        const float* __restrict__ link, const float* __restrict__ T,
        float* __restrict__ biasOut) {
    int x = blockIdx.x;
    int jt = x & 3, bi = x >> 2;
    int b = bi >> 8, i = bi & 255;
    int t = threadIdx.x;
    __shared__ float linksh[64 * 67];  // stride 67 to break bank conflicts
    __shared__ float Tsh[512];
    __shared__ float part[4 * 512];
    Tsh[t] = T[(size_t)bi * 512 + t];
    Tsh[256 + t] = T[(size_t)bi * 512 + 256 + t];
    {
        const float4* lp = (const float4*)(link + ((size_t)(bi * 256 + jt * 64)) * 64);
#pragma unroll
        for (int k = 0; k < 4; ++k) {
            int m = t + k * 256;  // f4 index 0..1023
            float4 v = lp[m];
            int j = m >> 4, c = (m & 15) * 4;
            float* dst = linksh + j * 67 + c;
            dst[0] = v.x; dst[1] = v.y; dst[2] = v.z; dst[3] = v.w;
        }
    }
    __syncthreads();
    int j = t & 63, rg = t >> 6;
    float pacc[8] = {0.f, 0.f, 0.f, 0.f, 0.f, 0.f, 0.f, 0.f};
    for (int rr = 0; rr < 16; ++rr) {
        int r = rg * 16 + rr;
        float lv = linksh[j * 67 + r];
#pragma unroll
        for (int h = 0; h < 8; ++h) pacc[h] += lv * Tsh[h * 64 + r];
    }
#pragma unroll
    for (int h = 0; h < 8; ++h) part[rg * 512 + h * 64 + j] = pacc[h];
    __syncthreads();
    int hp = t >> 6;
#pragma unroll
    for (int e = 0; e < 2; ++e) {
        int h = hp * 2 + e;
        float sum = part[h * 64 + j] + part[512 + h * 64 + j] +
                    part[1024 + h * 64 + j] + part[1536 + h * 64 + j];
        biasOut[((size_t)(b * 8 + h) * 256 + i) * 256 + jt * 64 + j] = sum;
    }
}

// ---------------------------------------------------------------------------
// K6: softmax: s = (qk + bias)*SCALE, mask, softmax over j -> alpha (in-place
// over the bias buffer = d_out alpha slot). grid = 1024 (bi), block = 256 (j)
__global__ __launch_bounds__(256) void softmax_kernel(
        const float* __restrict__ qk, const int* __restrict__ mask,
        float* __restrict__ alpha) {
    int bi = blockIdx.x;
    int b = bi >> 8, i = bi & 255;
    int t = threadIdx.x;
    __shared__ float redsh[64];
    int j = t;
    float s[8];
#pragma unroll
    for (int h = 0; h < 8; ++h) {
        size_t off = ((size_t)(b * 8 + h) * 256 + i) * 256 + j;
        s[h] = (qk[((size_t)(b * 8 + h) * 256 + i) * 256 + j] + alpha[off]) * SCALE_;
    }
    if (mask[(b * 256 + i) * 256 + j] == 0) {
#pragma unroll
        for (int h = 0; h < 8; ++h) s[h] = -1e9f;
    }
    int lane = t & 63, wv = t >> 6;
#pragma unroll
    for (int h = 0; h < 8; ++h) {
        float v = s[h];
        for (int off = 32; off > 0; off >>= 1) v = fmaxf(v, __shfl_xor(v, off));
        if (lane == 0) redsh[h * 4 + wv] = v;
    }
    __syncthreads();
    float mx[8];
#pragma unroll
    for (int h = 0; h < 8; ++h)
        mx[h] = fmaxf(fmaxf(redsh[h * 4 + 0], redsh[h * 4 + 1]),
                      fmaxf(redsh[h * 4 + 2], redsh[h * 4 + 3]));
    __syncthreads();
#pragma unroll
    for (int h = 0; h < 8; ++h) {
        float e = __expf(s[h] - mx[h]);
        s[h] = e;
        float v = e;
        for (int off = 32; off > 0; off >>= 1) v += __shfl_xor(v, off);
        if (lane == 0) redsh[h * 4 + wv] = v;
    }
    __syncthreads();
#pragma unroll
    for (int h = 0; h < 8; ++h) {
        float esum = redsh[h * 4 + 0] + redsh[h * 4 + 1] +
                     redsh[h * 4 + 2] + redsh[h * 4 + 3];
        alpha[((size_t)(b * 8 + h) * 256 + i) * 256 + j] = s[h] * (1.f / esum);
    }
}

// ---------------------------------------------------------------------------
// K7: S-partials: Spart[(bi*2+jt)][h*64+r] = sum_{j in 128-tile} alpha[h][j]*link[j][r]
// grid = 2048, block = 256. link staged coalesced -> LDS (L3-hot re-read).
__global__ __launch_bounds__(256) void spart_kernel(
        const float* __restrict__ link, const float* __restrict__ alpha,
        float* __restrict__ Spart) {
    int x = blockIdx.x;
    int jt = x & 1, bi = x >> 1;
    int b = bi >> 8, i = bi & 255;
    int t = threadIdx.x;
    __shared__ float linksh[128 * 67];  // 33.5 KB
    __shared__ float ash[1024];         // [h][128]
    __shared__ float part[4 * 512];
    {
        const float4* lp = (const float4*)(link + ((size_t)(bi * 256 + jt * 128)) * 64);
#pragma unroll
        for (int k = 0; k < 8; ++k) {
            int m = t + k * 256;  // f4 index 0..2047
            float4 v = lp[m];
            int j = m >> 4, c = (m & 15) * 4;
            float* dst = linksh + j * 67 + c;
            dst[0] = v.x; dst[1] = v.y; dst[2] = v.z; dst[3] = v.w;
        }
    }
#pragma unroll
    for (int k = 0; k < 4; ++k) {
        int m = t + k * 256;
        int h = m >> 7, j = m & 127;
        ash[m] = alpha[((size_t)(b * 8 + h) * 256 + i) * 256 + jt * 128 + j];
    }
    __syncthreads();
    int r = t & 63, jg = t >> 6;
    float pacc[8] = {0.f, 0.f, 0.f, 0.f, 0.f, 0.f, 0.f, 0.f};
    for (int jj = 0; jj < 32; ++jj) {
        int j = jg * 32 + jj;
        float lv = linksh[j * 67 + r];
#pragma unroll
        for (int h = 0; h < 8; ++h) pacc[h] += ash[h * 128 + j] * lv;
    }
#pragma unroll
    for (int h = 0; h < 8; ++h) part[jg * 512 + h * 64 + r] = pacc[h];
    __syncthreads();
    for (int hr = t; hr < 512; hr += 256) {
        float sum = part[hr] + part[512 + hr] + part[1024 + hr] + part[1536 + hr];
        Spart[(size_t)x * 512 + hr] = sum;
    }
}

// ---------------------------------------------------------------------------
// K8: Zx[b,h,i,dv] = sum_j alpha[b,h,i,j] * Xv[b,h,j,dv]  — batched tiled GEMM
// grid = 32 bh * 8 itiles = 256, block = 256, 4 outs/thread
__global__ __launch_bounds__(256) void zx_kernel(
        const float* __restrict__ alpha, const float* __restrict__ Xv,
        float* __restrict__ Zx) {
    int x = blockIdx.x;
    int it = x & 7, bh = x >> 3;
    int t = threadIdx.x;
    __shared__ float ash[32 * 64];   // [i][j-chunk] 8 KB
    __shared__ float xvsh[64 * 32];  // [j][dv] 8 KB
    int dv = t & 31, ig = t >> 5;
    float acc[4] = {0.f, 0.f, 0.f, 0.f};
    for (int cc = 0; cc < 4; ++cc) {
        __syncthreads();
#pragma unroll
        for (int k = 0; k < 2; ++k) {
            int m = t + k * 256;  // f4 index 0..511
            int i = m >> 4, jq = m & 15;
            float4 v = *(const float4*)(alpha + ((size_t)(bh * 256 + it * 32 + i)) * 256 + cc * 64 + jq * 4);
            float* dst = ash + i * 64 + jq * 4;
            dst[0] = v.x; dst[1] = v.y; dst[2] = v.z; dst[3] = v.w;
            ((float4*)xvsh)[m] = *(const float4*)(Xv + ((size_t)(bh * 256 + cc * 64)) * 32 + m * 4);
        }
        __syncthreads();
        for (int j = 0; j < 64; ++j) {
            float xv = xvsh[j * 32 + dv];
#pragma unroll
            for (int ii = 0; ii < 4; ++ii)
                acc[ii] += ash[(ig * 4 + ii) * 64 + j] * xv;
        }
    }
#pragma unroll
    for (int ii = 0; ii < 4; ++ii)
        Zx[((size_t)(bh * 256 + it * 32 + ig * 4 + ii)) * 32 + dv] = acc[ii];
}

// ---------------------------------------------------------------------------
// K9: Z-finalize (Spart reduce + S.Ev + Zx) -> GEMM @Wo + residual -> LayerNorm
// grid = 256 (4 rows each), block = 256 (col)
__global__ __launch_bounds__(256) void outz_kernel(
        const float* __restrict__ Spart, const float* __restrict__ Zx,
        const float* __restrict__ Ev, const float* __restrict__ Wo,
        const float* __restrict__ q, const float* __restrict__ gamma,
        const float* __restrict__ beta, float* __restrict__ out) {
    int blk = blockIdx.x;
    int t = threadIdx.x;
    __shared__ float Ssh[4 * 512];  // 8 KB
    __shared__ float zsh[4 * 256];  // 4 KB
    __shared__ float redsh[32];
    for (int m = t; m < 2048; m += 256) {
        int rr = m >> 9, hr = m & 511;
        size_t bi = (size_t)(blk * 4 + rr);
        Ssh[m] = Spart[bi * 1024 + hr] + Spart[bi * 1024 + 512 + hr];
    }
    __syncthreads();
    int h = t >> 5, dv = t & 31;
    int row0 = blk * 4;
    int b = row0 >> 8;
    float z[4];
#pragma unroll
    for (int rr = 0; rr < 4; ++rr) {
        int i = (row0 + rr) & 255;
        z[rr] = Zx[((size_t)((b * 8 + h) * 256 + i)) * 32 + dv];
    }
    for (int r = 0; r < 64; ++r) {
        float ev = Ev[r * 256 + h * 32 + dv];
#pragma unroll
        for (int rr = 0; rr < 4; ++rr) z[rr] += Ssh[rr * 512 + h * 64 + r] * ev;
    }
#pragma unroll
    for (int rr = 0; rr < 4; ++rr) zsh[rr * 256 + t] = z[rr];
    __syncthreads();
    float acc[4];
#pragma unroll
    for (int rr = 0; rr < 4; ++rr) acc[rr] = q[(row0 + rr) * 256 + t];
    for (int d4 = 0; d4 < 64; ++d4) {
        float w0 = Wo[(d4 * 4 + 0) * 256 + t];
        float w1 = Wo[(d4 * 4 + 1) * 256 + t];
        float w2 = Wo[(d4 * 4 + 2) * 256 + t];
        float w3 = Wo[(d4 * 4 + 3) * 256 + t];
#pragma unroll
        for (int rr = 0; rr < 4; ++rr) {
            float4 zv = *(const float4*)(zsh + rr * 256 + d4 * 4);
            acc[rr] += zv.x * w0 + zv.y * w1 + zv.z * w2 + zv.w * w3;
        }
    }
    int lane = t & 63, wv = t >> 6;
#pragma unroll
    for (int rr = 0; rr < 4; ++rr) {
        float v = acc[rr], v2 = acc[rr] * acc[rr];
        for (int off = 32; off > 0; off >>= 1) {
            v += __shfl_xor(v, off);
            v2 += __shfl_xor(v2, off);
        }
        if (lane == 0) {
            redsh[rr * 8 + wv] = v;
            redsh[rr * 8 + 4 + wv] = v2;
        }
    }
    __syncthreads();
#pragma unroll
    for (int rr = 0; rr < 4; ++rr) {
        float sum = redsh[rr * 8 + 0] + redsh[rr * 8 + 1] + redsh[rr * 8 + 2] + redsh[rr * 8 + 3];
        float sum2 = redsh[rr * 8 + 4] + redsh[rr * 8 + 5] + redsh[rr * 8 + 6] + redsh[rr * 8 + 7];
        float mu = sum * (1.f / 256.f);
        float var = sum2 * (1.f / 256.f) - mu * mu;
        float dev = acc[rr] - mu;
        out[(row0 + rr) * 256 + t] = dev * rsqrtf(var + EPS_) * gamma[t] + beta[t];
    }
}

// ---------------------------------------------------------------------------
extern "C" void kernel_launch(void* const* d_in, const int* in_sizes, int n_in,
                              void* d_out, int out_size, void* d_ws, size_t ws_size,
                              hipStream_t stream) {
    const float* q     = (const float*)d_in[0];
    const int*   mask  = (const int*)d_in[3];
    const float* link  = (const float*)d_in[4];
    const float* Wq    = (const float*)d_in[5];
    const float* Wk    = (const float*)d_in[6];
    const float* Wr    = (const float*)d_in[7];
    const float* Wv    = (const float*)d_in[8];
    const float* Wvv   = (const float*)d_in[9];
    const float* relE  = (const float*)d_in[10];
    const float* Wo    = (const float*)d_in[11];
    const float* gamma = (const float*)d_in[12];
    const float* beta  = (const float*)d_in[13];

    float* out   = (float*)d_out;
    float* alpha = out + B_ * N_ * D_;      // [B,H,N,N]; holds bias then alpha

    float* ws    = (float*)d_ws;
    float* Ek    = ws;                         // 16384
    float* Ev    = Ek + 16384;                 // 16384
    float* Mcat  = Ev + 16384;                 // 131072
    float* Xq    = Mcat + 131072;              // 262144
    float* Xk    = Xq + 262144;                // 262144
    float* Xv    = Xk + 262144;                // 262144
    float* T     = Xv + 262144;                // 524288
    float* qkbuf = T + 524288;                 // 2097152
    float* Spart = qkbuf + 2097152;            // 1048576
    float* Zx    = Spart + 1048576;            // 262144  (total ~19.5 MB)

    ekev_kernel<<<128, 256, 0, stream>>>(relE, Wr, Wvv, Ek, Ev);
    mcat_kernel<<<256, 256, 0, stream>>>(Wq, Ek, Mcat);
    projT_kernel<<<640, 256, 0, stream>>>(q, Wq, Wk, Wv, Mcat, Xq, Xk, Xv, T);
    qk_kernel<<<512, 256, 0, stream>>>(Xq, Xk, qkbuf);
    bias_kernel<<<4096, 256, 0, stream>>>(link, T, alpha);
    softmax_kernel<<<1024, 256, 0, stream>>>(qkbuf, mask, alpha);
    spart_kernel<<<2048, 256, 0, stream>>>(link, alpha, Spart);
    zx_kernel<<<256, 256, 0, stream>>>(alpha, Xv, Zx);
    outz_kernel<<<256, 256, 0, stream>>>(Spart, Zx, Ev, Wo, q, gamma, beta, out);
}